// Round 3
// baseline (968.966 us; speedup 1.0000x reference)
//
#include <hip/hip_runtime.h>

// GraphSAGE (2x SAGEConv mean + global_mean_pool) on MI355X.
// Pipeline: x->bf16 | CSR build (deg, scan, scatter) | agg1 (mean of x over
// in-edges) | GEMM1 h=relu([agg1|x]@[W1l;W1r]+b1) | t=h@W2l | agg2 (mean t) |
// t2=h@W2r | pool atomics | divide.
// ws usage ~92 MB (bufA: xb/t/t2 aliased, bufB: agg1/agg2 aliased).

constexpr int NN = 100000;    // nodes
constexpr int NE = 3200000;   // edges
constexpr int C1 = 128;       // IN_C == HID_C
constexpr int C2 = 64;        // OUT_C
constexpr int NG = 1024;      // graphs

typedef unsigned int u32;
typedef unsigned short u16;

__device__ __forceinline__ float bf2f(u32 u) { return __uint_as_float(u << 16); }
__device__ __forceinline__ u32 f2bf(float f) {            // RNE f32->bf16 bits
  u32 u = __float_as_uint(f);
  u += 0x7fffu + ((u >> 16) & 1u);
  return u >> 16;
}
__device__ __forceinline__ u32 pack2(float a, float b) { return f2bf(a) | (f2bf(b) << 16); }

// ---------------- x -> bf16 ----------------
__global__ __launch_bounds__(256)
void sage_x2bf(const float* __restrict__ x, u16* __restrict__ xb) {
  const int i = blockIdx.x * 256 + threadIdx.x;       // one float4 per thread
  if (i >= NN * C1 / 4) return;
  const float4 v = ((const float4*)x)[i];
  uint2 o;
  o.x = pack2(v.x, v.y);
  o.y = pack2(v.z, v.w);
  ((uint2*)xb)[i] = o;
}

// ---------------- CSR build ----------------
__global__ __launch_bounds__(256)
void sage_deg(const int* __restrict__ edst, int* __restrict__ deg) {
  const int e = blockIdx.x * 256 + threadIdx.x;
  if (e < NE) atomicAdd(&deg[edst[e]], 1);
}

__global__ __launch_bounds__(512)
void sage_scan1(const int* __restrict__ deg, int* __restrict__ offs,
                int* __restrict__ partials) {
  __shared__ int s[512];
  const int tid = threadIdx.x;
  const int i = blockIdx.x * 512 + tid;
  const int v = (i < NN) ? deg[i] : 0;
  s[tid] = v;
  __syncthreads();
  for (int d = 1; d < 512; d <<= 1) {
    const int add = (tid >= d) ? s[tid - d] : 0;
    __syncthreads();
    s[tid] += add;
    __syncthreads();
  }
  if (i < NN) offs[i] = s[tid] - v;                   // block-local exclusive
  if (tid == 511) partials[blockIdx.x] = s[511];      // block total
}

__global__ __launch_bounds__(256)
void sage_scan2(int* __restrict__ partials, int nb) {  // nb <= 256
  __shared__ int s[256];
  const int tid = threadIdx.x;
  const int v = (tid < nb) ? partials[tid] : 0;
  s[tid] = v;
  __syncthreads();
  for (int d = 1; d < 256; d <<= 1) {
    const int add = (tid >= d) ? s[tid - d] : 0;
    __syncthreads();
    s[tid] += add;
    __syncthreads();
  }
  if (tid < nb) partials[tid] = s[tid] - v;           // exclusive
}

__global__ __launch_bounds__(512)
void sage_scan3(int* __restrict__ offs, const int* __restrict__ partials,
                int* __restrict__ cursor) {
  const int i = blockIdx.x * 512 + threadIdx.x;
  if (i < NN) {
    const int o = offs[i] + partials[blockIdx.x];
    offs[i] = o;
    cursor[i] = o;
  }
  if (i == 0) offs[NN] = NE;                          // sum(deg) == NE
}

__global__ __launch_bounds__(256)
void sage_scatter(const int* __restrict__ esrc, const int* __restrict__ edst,
                  int* __restrict__ cursor, int* __restrict__ csr) {
  const int e = blockIdx.x * 256 + threadIdx.x;
  if (e < NE) {
    const int p = atomicAdd(&cursor[edst[e]], 1);
    csr[p] = esrc[e];
  }
}

// ------------- aggregation: mean over in-neighbors -------------
// wave per node; lane owns 2 of 128 bf16 channels, fp32 accumulate.
__global__ __launch_bounds__(256)
void sage_agg1(const int* __restrict__ offs, const int* __restrict__ csr,
               const u16* __restrict__ xb, u16* __restrict__ aggb) {
  const int node = blockIdx.x * 4 + (threadIdx.x >> 6);
  const int lane = threadIdx.x & 63;
  if (node >= NN) return;
  const int beg = offs[node], end = offs[node + 1];
  float ax = 0.f, ay = 0.f;
  const u16* xbase = xb + lane * 2;
  int e = beg;
  for (; e + 4 <= end; e += 4) {
    const int i0 = csr[e], i1 = csr[e + 1], i2 = csr[e + 2], i3 = csr[e + 3];
    const u32 v0 = *(const u32*)(xbase + i0 * C1);
    const u32 v1 = *(const u32*)(xbase + i1 * C1);
    const u32 v2 = *(const u32*)(xbase + i2 * C1);
    const u32 v3 = *(const u32*)(xbase + i3 * C1);
    ax += bf2f(v0 & 0xffffu) + bf2f(v1 & 0xffffu) + bf2f(v2 & 0xffffu) + bf2f(v3 & 0xffffu);
    ay += bf2f(v0 >> 16) + bf2f(v1 >> 16) + bf2f(v2 >> 16) + bf2f(v3 >> 16);
  }
  for (; e < end; ++e) {
    const u32 v = *(const u32*)(xbase + csr[e] * C1);
    ax += bf2f(v & 0xffffu);
    ay += bf2f(v >> 16);
  }
  const float inv = 1.0f / fmaxf((float)(end - beg), 1.0f);
  *(u32*)(aggb + node * C1 + lane * 2) = pack2(ax * inv, ay * inv);
}

// wave per node; lane owns 1 of 64 fp32 channels.
__global__ __launch_bounds__(256)
void sage_agg2(const int* __restrict__ offs, const int* __restrict__ csr,
               const float* __restrict__ t, float* __restrict__ agg) {
  const int node = blockIdx.x * 4 + (threadIdx.x >> 6);
  const int lane = threadIdx.x & 63;
  if (node >= NN) return;
  const int beg = offs[node], end = offs[node + 1];
  float a = 0.f;
  const float* tb = t + lane;
  int e = beg;
  for (; e + 4 <= end; e += 4) {
    const int i0 = csr[e], i1 = csr[e + 1], i2 = csr[e + 2], i3 = csr[e + 3];
    a += tb[i0 * C2] + tb[i1 * C2] + tb[i2 * C2] + tb[i3 * C2];
  }
  for (; e < end; ++e) a += tb[csr[e] * C2];
  agg[node * C2 + lane] = a / fmaxf((float)(end - beg), 1.0f);
}

// ------------- fp32 vector GEMM: acc[4 rows][8 cols] per thread -------------
// A: [NN,128] bf16, W: [128,COLS] fp32. A loads are wave-broadcast (16B/row),
// W loads are coalesced float4 rows reused through L1.
template <int COLS>
__device__ __forceinline__ void gemm_pass(const u16* __restrict__ A,
                                          const float* __restrict__ W,
                                          int n0, int c0, float acc[4][8]) {
  for (int k = 0; k < C1; k += 8) {
    uint4 av[4];
#pragma unroll
    for (int i = 0; i < 4; ++i) {
      int r = n0 + i;
      r = (r < NN) ? r : (NN - 1);                    // clamp; store is guarded
      av[i] = *(const uint4*)(A + r * C1 + k);
    }
#pragma unroll
    for (int kk2 = 0; kk2 < 4; ++kk2) {
#pragma unroll
      for (int half = 0; half < 2; ++half) {
        const int kb = k + kk2 * 2 + half;
        const float4 wa = *(const float4*)(W + kb * COLS + c0);
        const float4 wb = *(const float4*)(W + kb * COLS + c0 + 4);
#pragma unroll
        for (int i = 0; i < 4; ++i) {
          const u32 word = (kk2 == 0) ? av[i].x : (kk2 == 1) ? av[i].y
                           : (kk2 == 2) ? av[i].z : av[i].w;
          const float a = half ? bf2f(word >> 16) : bf2f(word & 0xffffu);
          acc[i][0] += a * wa.x; acc[i][1] += a * wa.y;
          acc[i][2] += a * wa.z; acc[i][3] += a * wa.w;
          acc[i][4] += a * wb.x; acc[i][5] += a * wb.y;
          acc[i][6] += a * wb.z; acc[i][7] += a * wb.w;
        }
      }
    }
  }
}

// h = relu(agg1 @ W1l + x @ W1r + b1), bf16 out. block: 16 colgroups x 16 rowgroups.
__global__ __launch_bounds__(256)
void sage_gemm1(const u16* __restrict__ A1, const u16* __restrict__ A2,
                const float* __restrict__ W1, const float* __restrict__ W2,
                const float* __restrict__ bias, u16* __restrict__ H) {
  const int tx = threadIdx.x & 15, ty = threadIdx.x >> 4;
  const int c0 = tx * 8;
  const int n0 = blockIdx.x * 64 + ty * 4;
  float acc[4][8] = {};
  gemm_pass<C1>(A1, W1, n0, c0, acc);
  gemm_pass<C1>(A2, W2, n0, c0, acc);
  float bv[8];
#pragma unroll
  for (int j = 0; j < 8; ++j) bv[j] = bias[c0 + j];
#pragma unroll
  for (int i = 0; i < 4; ++i) {
    const int r = n0 + i;
    if (r < NN) {
      uint4 o;
      o.x = pack2(fmaxf(acc[i][0] + bv[0], 0.f), fmaxf(acc[i][1] + bv[1], 0.f));
      o.y = pack2(fmaxf(acc[i][2] + bv[2], 0.f), fmaxf(acc[i][3] + bv[3], 0.f));
      o.z = pack2(fmaxf(acc[i][4] + bv[4], 0.f), fmaxf(acc[i][5] + bv[5], 0.f));
      o.w = pack2(fmaxf(acc[i][6] + bv[6], 0.f), fmaxf(acc[i][7] + bv[7], 0.f));
      *(uint4*)(H + r * C1 + c0) = o;
    }
  }
}

// OUT[NN,64] fp32 = A[NN,128](bf16) @ W[128,64]. block: 8 colgroups x 32 rowgroups.
__global__ __launch_bounds__(256)
void sage_gemm64(const u16* __restrict__ A, const float* __restrict__ W,
                 float* __restrict__ OUT) {
  const int tx = threadIdx.x & 7, ty = threadIdx.x >> 3;
  const int c0 = tx * 8;
  const int n0 = blockIdx.x * 128 + ty * 4;
  float acc[4][8] = {};
  gemm_pass<C2>(A, W, n0, c0, acc);
#pragma unroll
  for (int i = 0; i < 4; ++i) {
    const int r = n0 + i;
    if (r < NN) {
      *(float4*)(OUT + r * C2 + c0) =
          make_float4(acc[i][0], acc[i][1], acc[i][2], acc[i][3]);
      *(float4*)(OUT + r * C2 + c0 + 4) =
          make_float4(acc[i][4], acc[i][5], acc[i][6], acc[i][7]);
    }
  }
}

// ------------- pooling -------------
__global__ __launch_bounds__(256)
void sage_gcnt(const int* __restrict__ batch, int* __restrict__ gcnt) {
  const int n = blockIdx.x * 256 + threadIdx.x;
  if (n < NN) atomicAdd(&gcnt[batch[n]], 1);
}

__global__ __launch_bounds__(256)
void sage_pool(const float* __restrict__ t2, const float* __restrict__ agg2,
               const float* __restrict__ b2, const int* __restrict__ batch,
               float* __restrict__ pool) {
  const int i = blockIdx.x * 256 + threadIdx.x;
  if (i >= NN * C2) return;
  const int n = i >> 6, c = i & 63;
  const float v = t2[i] + agg2[i] + b2[c];
  atomicAdd(&pool[batch[n] * C2 + c], v);
}

__global__ __launch_bounds__(256)
void sage_out(const float* __restrict__ pool, const int* __restrict__ gcnt,
              float* __restrict__ out) {
  const int i = blockIdx.x * 256 + threadIdx.x;
  if (i >= NG * C2) return;
  out[i] = pool[i] / fmaxf((float)gcnt[i >> 6], 1.0f);
}

extern "C" void kernel_launch(void* const* d_in, const int* in_sizes, int n_in,
                              void* d_out, int out_size, void* d_ws, size_t ws_size,
                              hipStream_t stream) {
  (void)in_sizes; (void)n_in; (void)out_size; (void)ws_size;
  const float* x     = (const float*)d_in[0];
  const float* W1l   = (const float*)d_in[1];
  const float* b1    = (const float*)d_in[2];
  const float* W1r   = (const float*)d_in[3];
  const float* W2l   = (const float*)d_in[4];
  const float* b2    = (const float*)d_in[5];
  const float* W2r   = (const float*)d_in[6];
  const int*   ei    = (const int*)d_in[7];   // [2, NE]: row0 = src, row1 = dst
  const int*   batch = (const int*)d_in[8];
  const int* esrc = ei;
  const int* edst = ei + NE;
  float* out = (float*)d_out;

  // ---- workspace carve-out (~92 MB) ----
  char* base = (char*)d_ws;
  size_t off = 0;
  auto take = [&](size_t bytes) -> char* {
    char* p = base + off;
    off += (bytes + 255) & ~(size_t)255;
    return p;
  };
  int* deg      = (int*)take((size_t)NN * 4);
  int* offs     = (int*)take((size_t)(NN + 1) * 4);
  int* cursor   = (int*)take((size_t)NN * 4);
  int* partials = (int*)take(1024 * 4);
  int* csr      = (int*)take((size_t)NE * 4);
  char* bufA    = take((size_t)NN * 256);   // xb (bf16 NNx128) -> t/t2 (f32 NNx64)
  char* bufB    = take((size_t)NN * 256);   // agg1 (bf16)      -> agg2 (f32)
  u16*  hb      = (u16*)take((size_t)NN * 256);
  float* pool   = (float*)take((size_t)NG * C2 * 4);
  int*  gcnt    = (int*)take((size_t)NG * 4);

  u16*   xb    = (u16*)bufA;
  float* t     = (float*)bufA;
  u16*   agg1b = (u16*)bufB;
  float* agg2  = (float*)bufB;

  hipMemsetAsync(deg, 0, (size_t)NN * 4, stream);
  hipMemsetAsync(pool, 0, (size_t)NG * C2 * 4, stream);
  hipMemsetAsync(gcnt, 0, (size_t)NG * 4, stream);

  constexpr int SB = (NN + 511) / 512;      // scan blocks (196 <= 256)

  sage_x2bf<<<(NN * C1 / 4 + 255) / 256, 256, 0, stream>>>(x, xb);
  sage_deg<<<(NE + 255) / 256, 256, 0, stream>>>(edst, deg);
  sage_scan1<<<SB, 512, 0, stream>>>(deg, offs, partials);
  sage_scan2<<<1, 256, 0, stream>>>(partials, SB);
  sage_scan3<<<SB, 512, 0, stream>>>(offs, partials, cursor);
  sage_scatter<<<(NE + 255) / 256, 256, 0, stream>>>(esrc, edst, cursor, csr);

  // layer 1
  sage_agg1<<<(NN + 3) / 4, 256, 0, stream>>>(offs, csr, xb, agg1b);
  sage_gemm1<<<(NN + 63) / 64, 256, 0, stream>>>(agg1b, xb, W1l, W1r, b1, hb);

  // layer 2 (transform-then-aggregate: mean(h)@W2l == mean(h@W2l))
  sage_gemm64<<<(NN + 127) / 128, 256, 0, stream>>>(hb, W2l, t);    // t = h@W2l (xb dead)
  sage_agg2<<<(NN + 3) / 4, 256, 0, stream>>>(offs, csr, t, agg2);  // agg1 dead
  sage_gemm64<<<(NN + 127) / 128, 256, 0, stream>>>(hb, W2r, t);    // t = h@W2r (old t dead)

  // global mean pool
  sage_gcnt<<<(NN + 255) / 256, 256, 0, stream>>>(batch, gcnt);
  sage_pool<<<(NN * C2 + 255) / 256, 256, 0, stream>>>(t, agg2, b2, batch, pool);
  sage_out<<<(NG * C2 + 255) / 256, 256, 0, stream>>>(pool, gcnt, out);
}

// Round 4
// 833.859 us; speedup vs baseline: 1.1620x; 1.1620x over previous
//
#include <hip/hip_runtime.h>

// GraphSAGE (2x SAGEConv mean + global_mean_pool) on MI355X.
// R3: bucketed CSR scatter (kills 16x write-allocate amplification seen in R2
// profile: WRITE_SIZE 195MB for a 12.8MB csr), fp16 activations (xb/agg1/h/t),
// agg2 gathers fp16 t at 128B/row with 2 edges per wave.
// Pipeline: x->f16 | CSR build (deg, scan, bucketed scatter) | agg1 (mean x) |
// GEMM1 h=relu([agg1|x]@[W1l;W1r]+b1) | t=h@W2l (f16) | agg2 (mean t) |
// t2=h@W2r (f32) | pool atomics | divide.

constexpr int NN = 100000;    // nodes
constexpr int NE = 3200000;   // edges
constexpr int C1 = 128;       // IN_C == HID_C
constexpr int C2 = 64;        // OUT_C
constexpr int NG = 1024;      // graphs

constexpr int BSHIFT = 13;                      // 8192 nodes per bucket
constexpr int NB = (NN + (1 << BSHIFT) - 1) >> BSHIFT;   // 13 buckets

typedef unsigned int u32;
typedef unsigned short u16;

__device__ __forceinline__ float h2f(u32 bits16) {
  _Float16 h; u16 b = (u16)bits16;
  __builtin_memcpy(&h, &b, 2);
  return (float)h;
}
__device__ __forceinline__ u16 f2h(float f) {
  _Float16 h = (_Float16)f; u16 b;
  __builtin_memcpy(&b, &h, 2);
  return b;
}
__device__ __forceinline__ u32 packh2(float a, float b) {
  return (u32)f2h(a) | ((u32)f2h(b) << 16);
}

// ---------------- x -> fp16 ----------------
__global__ __launch_bounds__(256)
void sage_x2h(const float* __restrict__ x, u16* __restrict__ xh) {
  const int i = blockIdx.x * 256 + threadIdx.x;       // one float4 per thread
  if (i >= NN * C1 / 4) return;
  const float4 v = ((const float4*)x)[i];
  uint2 o;
  o.x = packh2(v.x, v.y);
  o.y = packh2(v.z, v.w);
  ((uint2*)xh)[i] = o;
}

// ---------------- CSR build ----------------
__global__ __launch_bounds__(256)
void sage_deg(const int* __restrict__ edst, int* __restrict__ deg) {
  const int e = blockIdx.x * 256 + threadIdx.x;
  if (e < NE) atomicAdd(&deg[edst[e]], 1);
}

__global__ __launch_bounds__(512)
void sage_scan1(const int* __restrict__ deg, int* __restrict__ offs,
                int* __restrict__ partials) {
  __shared__ int s[512];
  const int tid = threadIdx.x;
  const int i = blockIdx.x * 512 + tid;
  const int v = (i < NN) ? deg[i] : 0;
  s[tid] = v;
  __syncthreads();
  for (int d = 1; d < 512; d <<= 1) {
    const int add = (tid >= d) ? s[tid - d] : 0;
    __syncthreads();
    s[tid] += add;
    __syncthreads();
  }
  if (i < NN) offs[i] = s[tid] - v;                   // block-local exclusive
  if (tid == 511) partials[blockIdx.x] = s[511];      // block total
}

__global__ __launch_bounds__(256)
void sage_scan2(int* __restrict__ partials, int nb) {  // nb <= 256
  __shared__ int s[256];
  const int tid = threadIdx.x;
  const int v = (tid < nb) ? partials[tid] : 0;
  s[tid] = v;
  __syncthreads();
  for (int d = 1; d < 256; d <<= 1) {
    const int add = (tid >= d) ? s[tid - d] : 0;
    __syncthreads();
    s[tid] += add;
    __syncthreads();
  }
  if (tid < nb) partials[tid] = s[tid] - v;           // exclusive
}

__global__ __launch_bounds__(512)
void sage_scan3(int* __restrict__ offs, const int* __restrict__ partials,
                int* __restrict__ cursor) {
  const int i = blockIdx.x * 512 + threadIdx.x;
  if (i < NN) {
    const int o = offs[i] + partials[blockIdx.x];
    offs[i] = o;
    cursor[i] = o;
  }
  if (i == 0) offs[NN] = NE;                          // sum(deg) == NE
}

// Bucketed scatter: blockIdx.y = bucket of 8192 dst nodes. Each block streams
// a coalesced chunk of edges; only edges whose dst is in-bucket are written.
// csr writes land in a ~1MB window, cursor atomics in a 32KB window.
__global__ __launch_bounds__(256)
void sage_scatter_b(const int* __restrict__ esrc, const int* __restrict__ edst,
                    int* __restrict__ cursor, int* __restrict__ csr) {
  const int bucket = blockIdx.y;
  const int e0 = blockIdx.x * 4096 + threadIdx.x;
#pragma unroll
  for (int j = 0; j < 16; ++j) {
    const int e = e0 + j * 256;
    if (e < NE) {
      const int d = edst[e];
      if ((d >> BSHIFT) == bucket) {
        const int p = atomicAdd(&cursor[d], 1);
        csr[p] = esrc[e];
      }
    }
  }
}

// ------------- aggregation: mean over in-neighbors -------------
// wave per node; lane owns 2 of 128 fp16 channels, fp32 accumulate.
__global__ __launch_bounds__(256)
void sage_agg1(const int* __restrict__ offs, const int* __restrict__ csr,
               const u16* __restrict__ xh, u16* __restrict__ aggh) {
  const int node = blockIdx.x * 4 + (threadIdx.x >> 6);
  const int lane = threadIdx.x & 63;
  if (node >= NN) return;
  const int beg = offs[node], end = offs[node + 1];
  float ax = 0.f, ay = 0.f;
  const u16* xbase = xh + lane * 2;
  int e = beg;
  for (; e + 4 <= end; e += 4) {
    const int i0 = csr[e], i1 = csr[e + 1], i2 = csr[e + 2], i3 = csr[e + 3];
    const u32 v0 = *(const u32*)(xbase + i0 * C1);
    const u32 v1 = *(const u32*)(xbase + i1 * C1);
    const u32 v2 = *(const u32*)(xbase + i2 * C1);
    const u32 v3 = *(const u32*)(xbase + i3 * C1);
    ax += h2f(v0 & 0xffffu) + h2f(v1 & 0xffffu) + h2f(v2 & 0xffffu) + h2f(v3 & 0xffffu);
    ay += h2f(v0 >> 16) + h2f(v1 >> 16) + h2f(v2 >> 16) + h2f(v3 >> 16);
  }
  for (; e < end; ++e) {
    const u32 v = *(const u32*)(xbase + csr[e] * C1);
    ax += h2f(v & 0xffffu);
    ay += h2f(v >> 16);
  }
  const float inv = 1.0f / fmaxf((float)(end - beg), 1.0f);
  *(u32*)(aggh + node * C1 + lane * 2) = packh2(ax * inv, ay * inv);
}

// wave per node, 2 edges per iteration (half-wave each); t is fp16 [NN,64].
// lane (l = lane&31) owns channels 2l, 2l+1; halves combined via shfl_xor(32).
__global__ __launch_bounds__(256)
void sage_agg2(const int* __restrict__ offs, const int* __restrict__ csr,
               const u16* __restrict__ t, float* __restrict__ agg) {
  const int node = blockIdx.x * 4 + (threadIdx.x >> 6);
  const int lane = threadIdx.x & 63;
  if (node >= NN) return;
  const int beg = offs[node], end = offs[node + 1];
  const int hf = lane >> 5, l = lane & 31;
  const u16* tb = t + l * 2;
  float ax = 0.f, ay = 0.f;
  int e = beg + hf;
  for (; e + 2 < end; e += 4) {                       // 2 edges per half in flight
    const int s0 = csr[e], s1 = csr[e + 2];
    const u32 v0 = *(const u32*)(tb + s0 * C2);
    const u32 v1 = *(const u32*)(tb + s1 * C2);
    ax += h2f(v0 & 0xffffu) + h2f(v1 & 0xffffu);
    ay += h2f(v0 >> 16) + h2f(v1 >> 16);
  }
  if (e < end) {
    const u32 v = *(const u32*)(tb + csr[e] * C2);
    ax += h2f(v & 0xffffu);
    ay += h2f(v >> 16);
  }
  ax += __shfl_xor(ax, 32);
  ay += __shfl_xor(ay, 32);
  if (hf == 0) {
    const float inv = 1.0f / fmaxf((float)(end - beg), 1.0f);
    *(float2*)(agg + node * C2 + l * 2) = make_float2(ax * inv, ay * inv);
  }
}

// ------------- fp32 vector GEMM: acc[4 rows][8 cols] per thread -------------
// A: [NN,128] fp16, W: [128,COLS] fp32. A loads are wave-broadcast (16B/row),
// W loads are coalesced float4 rows reused through L1.
template <int COLS>
__device__ __forceinline__ void gemm_pass(const u16* __restrict__ A,
                                          const float* __restrict__ W,
                                          int n0, int c0, float acc[4][8]) {
  for (int k = 0; k < C1; k += 8) {
    uint4 av[4];
#pragma unroll
    for (int i = 0; i < 4; ++i) {
      int r = n0 + i;
      r = (r < NN) ? r : (NN - 1);                    // clamp; store is guarded
      av[i] = *(const uint4*)(A + r * C1 + k);
    }
#pragma unroll
    for (int kk2 = 0; kk2 < 4; ++kk2) {
#pragma unroll
      for (int half = 0; half < 2; ++half) {
        const int kb = k + kk2 * 2 + half;
        const float4 wa = *(const float4*)(W + kb * COLS + c0);
        const float4 wb = *(const float4*)(W + kb * COLS + c0 + 4);
#pragma unroll
        for (int i = 0; i < 4; ++i) {
          const u32 word = (kk2 == 0) ? av[i].x : (kk2 == 1) ? av[i].y
                           : (kk2 == 2) ? av[i].z : av[i].w;
          const float a = half ? h2f(word >> 16) : h2f(word & 0xffffu);
          acc[i][0] += a * wa.x; acc[i][1] += a * wa.y;
          acc[i][2] += a * wa.z; acc[i][3] += a * wa.w;
          acc[i][4] += a * wb.x; acc[i][5] += a * wb.y;
          acc[i][6] += a * wb.z; acc[i][7] += a * wb.w;
        }
      }
    }
  }
}

// h = relu(agg1 @ W1l + x @ W1r + b1), fp16 out. block: 16 colgroups x 16 rowgroups.
__global__ __launch_bounds__(256)
void sage_gemm1(const u16* __restrict__ A1, const u16* __restrict__ A2,
                const float* __restrict__ W1, const float* __restrict__ W2,
                const float* __restrict__ bias, u16* __restrict__ H) {
  const int tx = threadIdx.x & 15, ty = threadIdx.x >> 4;
  const int c0 = tx * 8;
  const int n0 = blockIdx.x * 64 + ty * 4;
  float acc[4][8] = {};
  gemm_pass<C1>(A1, W1, n0, c0, acc);
  gemm_pass<C1>(A2, W2, n0, c0, acc);
  float bv[8];
#pragma unroll
  for (int j = 0; j < 8; ++j) bv[j] = bias[c0 + j];
#pragma unroll
  for (int i = 0; i < 4; ++i) {
    const int r = n0 + i;
    if (r < NN) {
      uint4 o;
      o.x = packh2(fmaxf(acc[i][0] + bv[0], 0.f), fmaxf(acc[i][1] + bv[1], 0.f));
      o.y = packh2(fmaxf(acc[i][2] + bv[2], 0.f), fmaxf(acc[i][3] + bv[3], 0.f));
      o.z = packh2(fmaxf(acc[i][4] + bv[4], 0.f), fmaxf(acc[i][5] + bv[5], 0.f));
      o.w = packh2(fmaxf(acc[i][6] + bv[6], 0.f), fmaxf(acc[i][7] + bv[7], 0.f));
      *(uint4*)(H + r * C1 + c0) = o;
    }
  }
}

// OUT[NN,64] = A[NN,128](fp16) @ W[128,64]; F16OUT picks fp16 vs fp32 output.
template <bool F16OUT>
__global__ __launch_bounds__(256)
void sage_gemm64(const u16* __restrict__ A, const float* __restrict__ W,
                 void* __restrict__ OUT) {
  const int tx = threadIdx.x & 7, ty = threadIdx.x >> 3;
  const int c0 = tx * 8;
  const int n0 = blockIdx.x * 128 + ty * 4;
  float acc[4][8] = {};
  gemm_pass<C2>(A, W, n0, c0, acc);
#pragma unroll
  for (int i = 0; i < 4; ++i) {
    const int r = n0 + i;
    if (r < NN) {
      if (F16OUT) {
        uint2 o;
        o.x = packh2(acc[i][0], acc[i][1]);
        o.y = packh2(acc[i][2], acc[i][3]);
        uint2 o2;
        o2.x = packh2(acc[i][4], acc[i][5]);
        o2.y = packh2(acc[i][6], acc[i][7]);
        uint4 w = make_uint4(o.x, o.y, o2.x, o2.y);
        *(uint4*)((u16*)OUT + r * C2 + c0) = w;
      } else {
        float* o = (float*)OUT;
        *(float4*)(o + r * C2 + c0) =
            make_float4(acc[i][0], acc[i][1], acc[i][2], acc[i][3]);
        *(float4*)(o + r * C2 + c0 + 4) =
            make_float4(acc[i][4], acc[i][5], acc[i][6], acc[i][7]);
      }
    }
  }
}

// ------------- pooling -------------
__global__ __launch_bounds__(256)
void sage_gcnt(const int* __restrict__ batch, int* __restrict__ gcnt) {
  const int n = blockIdx.x * 256 + threadIdx.x;
  if (n < NN) atomicAdd(&gcnt[batch[n]], 1);
}

__global__ __launch_bounds__(256)
void sage_pool(const float* __restrict__ t2, const float* __restrict__ agg2,
               const float* __restrict__ b2, const int* __restrict__ batch,
               float* __restrict__ pool) {
  const int i = blockIdx.x * 256 + threadIdx.x;
  if (i >= NN * C2) return;
  const int n = i >> 6, c = i & 63;
  const float v = t2[i] + agg2[i] + b2[c];
  atomicAdd(&pool[batch[n] * C2 + c], v);
}

__global__ __launch_bounds__(256)
void sage_out(const float* __restrict__ pool, const int* __restrict__ gcnt,
              float* __restrict__ out) {
  const int i = blockIdx.x * 256 + threadIdx.x;
  if (i >= NG * C2) return;
  out[i] = pool[i] / fmaxf((float)gcnt[i >> 6], 1.0f);
}

extern "C" void kernel_launch(void* const* d_in, const int* in_sizes, int n_in,
                              void* d_out, int out_size, void* d_ws, size_t ws_size,
                              hipStream_t stream) {
  (void)in_sizes; (void)n_in; (void)out_size; (void)ws_size;
  const float* x     = (const float*)d_in[0];
  const float* W1l   = (const float*)d_in[1];
  const float* b1    = (const float*)d_in[2];
  const float* W1r   = (const float*)d_in[3];
  const float* W2l   = (const float*)d_in[4];
  const float* b2    = (const float*)d_in[5];
  const float* W2r   = (const float*)d_in[6];
  const int*   ei    = (const int*)d_in[7];   // [2, NE]: row0 = src, row1 = dst
  const int*   batch = (const int*)d_in[8];
  const int* esrc = ei;
  const int* edst = ei + NE;
  float* out = (float*)d_out;

  // ---- workspace carve-out (~91 MB) ----
  char* base = (char*)d_ws;
  size_t off = 0;
  auto take = [&](size_t bytes) -> char* {
    char* p = base + off;
    off += (bytes + 255) & ~(size_t)255;
    return p;
  };
  int* deg      = (int*)take((size_t)NN * 4);
  int* offs     = (int*)take((size_t)(NN + 1) * 4);
  int* cursor   = (int*)take((size_t)NN * 4);
  int* partials = (int*)take(1024 * 4);
  int* csr      = (int*)take((size_t)NE * 4);
  char* bufA    = take((size_t)NN * 256);   // xh (f16 NNx128) -> t (f16 NNx64) -> t2 (f32 NNx64)
  char* bufB    = take((size_t)NN * 256);   // agg1 (f16 NNx128) -> agg2 (f32 NNx64)
  u16*  hb      = (u16*)take((size_t)NN * 256);
  float* pool   = (float*)take((size_t)NG * C2 * 4);
  int*  gcnt    = (int*)take((size_t)NG * 4);

  u16*   xh    = (u16*)bufA;
  u16*   t     = (u16*)bufA;                // fp16 h@W2l (xh dead by then)
  float* t2    = (float*)bufA;              // fp32 h@W2r (t dead by then)
  u16*   agg1h = (u16*)bufB;
  float* agg2  = (float*)bufB;

  hipMemsetAsync(deg, 0, (size_t)NN * 4, stream);
  hipMemsetAsync(pool, 0, (size_t)NG * C2 * 4, stream);
  hipMemsetAsync(gcnt, 0, (size_t)NG * 4, stream);

  constexpr int SB = (NN + 511) / 512;      // scan blocks (196 <= 256)

  sage_x2h<<<(NN * C1 / 4 + 255) / 256, 256, 0, stream>>>(x, xh);
  sage_deg<<<(NE + 255) / 256, 256, 0, stream>>>(edst, deg);
  sage_scan1<<<SB, 512, 0, stream>>>(deg, offs, partials);
  sage_scan2<<<1, 256, 0, stream>>>(partials, SB);
  sage_scan3<<<SB, 512, 0, stream>>>(offs, partials, cursor);
  dim3 sgrid((NE + 4095) / 4096, NB);
  sage_scatter_b<<<sgrid, 256, 0, stream>>>(esrc, edst, cursor, csr);

  // layer 1
  sage_agg1<<<(NN + 3) / 4, 256, 0, stream>>>(offs, csr, xh, agg1h);
  sage_gemm1<<<(NN + 63) / 64, 256, 0, stream>>>(agg1h, xh, W1l, W1r, b1, hb);

  // layer 2 (transform-then-aggregate: mean(h)@W2l == mean(h@W2l))
  sage_gemm64<true><<<(NN + 127) / 128, 256, 0, stream>>>(hb, W2l, t);   // t = h@W2l (f16)
  sage_agg2<<<(NN + 3) / 4, 256, 0, stream>>>(offs, csr, t, agg2);       // agg1 dead
  sage_gemm64<false><<<(NN + 127) / 128, 256, 0, stream>>>(hb, W2r, t2); // t2 = h@W2r (f32)

  // global mean pool
  sage_gcnt<<<(NN + 255) / 256, 256, 0, stream>>>(batch, gcnt);
  sage_pool<<<(NN * C2 + 255) / 256, 256, 0, stream>>>(t2, agg2, b2, batch, pool);
  sage_out<<<(NG * C2 + 255) / 256, 256, 0, stream>>>(pool, gcnt, out);
}

// Round 5
// 686.689 us; speedup vs baseline: 1.4111x; 1.2143x over previous
//
#include <hip/hip_runtime.h>

// GraphSAGE (2x SAGEConv mean + global_mean_pool) on MI355X.
// R4: (1) scatter with bucket<->XCD affinity (bucket = blockIdx.x & 7): all
//     writers of a bucket's ~1.6MB csr window sit on ONE XCD L2 -> full-line
//     flushes (R3 profile showed WRITE_SIZE 194MB for 12.8MB of csr because
//     13 buckets were written from all 8 XCDs concurrently = partial lines).
// (2) fp16 MFMA GEMMs (mfma_f32_16x16x32_f16): gemm1 = [agg1|x]@[W1l;W1r]
//     K=256 dual-A; gemm2 = h@[W2l|W2r] N=128 fused (t and t2 in one pass).
//     Weights pre-transposed to [N][K] fp16 by prep kernel; LDS A-tile with
//     16B-chunk XOR swizzle -> conflict-free ds_read_b128.

constexpr int NN = 100000;    // nodes
constexpr int NE = 3200000;   // edges
constexpr int C1 = 128;       // IN_C == HID_C
constexpr int C2 = 64;        // OUT_C
constexpr int NG = 1024;      // graphs

constexpr int NBUCK = 8;      // scatter buckets == XCD count
constexpr int BDIV  = 12500;  // nodes per bucket (8 * 12500 >= NN)

typedef unsigned int u32;
typedef unsigned short u16;
typedef _Float16 f16;
typedef f16 f16x8 __attribute__((ext_vector_type(8)));
typedef float f32x4 __attribute__((ext_vector_type(4)));

__device__ __forceinline__ float h2f(u32 bits16) {
  f16 h; u16 b = (u16)bits16;
  __builtin_memcpy(&h, &b, 2);
  return (float)h;
}
__device__ __forceinline__ u16 f2h(float f) {
  f16 h = (f16)f; u16 b;
  __builtin_memcpy(&b, &h, 2);
  return b;
}
__device__ __forceinline__ u32 packh2(float a, float b) {
  return (u32)f2h(a) | ((u32)f2h(b) << 16);
}

// ---------------- x -> fp16 ----------------
__global__ __launch_bounds__(256)
void sage_x2h(const float* __restrict__ x, u16* __restrict__ xh) {
  const int i = blockIdx.x * 256 + threadIdx.x;       // one float4 per thread
  if (i >= NN * C1 / 4) return;
  const float4 v = ((const float4*)x)[i];
  uint2 o;
  o.x = packh2(v.x, v.y);
  o.y = packh2(v.z, v.w);
  ((uint2*)xh)[i] = o;
}

// ------------- weights -> fp16, transposed [N][K] -------------
// wt1: [128 n][256 k]  (k<128: W1l, k>=128: W1r)    for gemm1
// wt2: [128 n][128 k]  (n<64: W2l col n, n>=64: W2r col n-64) for gemm2
__global__ __launch_bounds__(256)
void sage_wprep(const float* __restrict__ W1l, const float* __restrict__ W1r,
                const float* __restrict__ W2l, const float* __restrict__ W2r,
                u16* __restrict__ wt1, u16* __restrict__ wt2) {
  const int id = blockIdx.x * 256 + threadIdx.x;
  if (id < 128 * 256) {
    const int n = id >> 8, k = id & 255;
    const float v = (k < 128) ? W1l[k * 128 + n] : W1r[(k - 128) * 128 + n];
    wt1[id] = f2h(v);
  } else if (id < 128 * 256 + 128 * 128) {
    const int id2 = id - 128 * 256;
    const int n = id2 >> 7, k = id2 & 127;
    const float v = (n < 64) ? W2l[k * 64 + n] : W2r[k * 64 + (n - 64)];
    wt2[id2] = f2h(v);
  }
}

// ---------------- CSR build ----------------
__global__ __launch_bounds__(256)
void sage_deg(const int* __restrict__ edst, int* __restrict__ deg) {
  const int e = blockIdx.x * 256 + threadIdx.x;
  if (e < NE) atomicAdd(&deg[edst[e]], 1);
}

__global__ __launch_bounds__(512)
void sage_scan1(const int* __restrict__ deg, int* __restrict__ offs,
                int* __restrict__ partials) {
  __shared__ int s[512];
  const int tid = threadIdx.x;
  const int i = blockIdx.x * 512 + tid;
  const int v = (i < NN) ? deg[i] : 0;
  s[tid] = v;
  __syncthreads();
  for (int d = 1; d < 512; d <<= 1) {
    const int add = (tid >= d) ? s[tid - d] : 0;
    __syncthreads();
    s[tid] += add;
    __syncthreads();
  }
  if (i < NN) offs[i] = s[tid] - v;                   // block-local exclusive
  if (tid == 511) partials[blockIdx.x] = s[511];      // block total
}

__global__ __launch_bounds__(256)
void sage_scan2(int* __restrict__ partials, int nb) {  // nb <= 256
  __shared__ int s[256];
  const int tid = threadIdx.x;
  const int v = (tid < nb) ? partials[tid] : 0;
  s[tid] = v;
  __syncthreads();
  for (int d = 1; d < 256; d <<= 1) {
    const int add = (tid >= d) ? s[tid - d] : 0;
    __syncthreads();
    s[tid] += add;
    __syncthreads();
  }
  if (tid < nb) partials[tid] = s[tid] - v;           // exclusive
}

__global__ __launch_bounds__(512)
void sage_scan3(int* __restrict__ offs, const int* __restrict__ partials,
                int* __restrict__ cursor) {
  const int i = blockIdx.x * 512 + threadIdx.x;
  if (i < NN) {
    const int o = offs[i] + partials[blockIdx.x];
    offs[i] = o;
    cursor[i] = o;
  }
  if (i == 0) offs[NN] = NE;                          // sum(deg) == NE
}

// Scatter with bucket<->XCD affinity: bucket = blockIdx.x & 7. Dispatch
// round-robins consecutive blocks over the 8 XCDs, so all blocks of one
// bucket run on one XCD; its ~1.6MB csr window stays in that L2 and lines
// fill completely before flush. Correctness does not depend on the mapping.
__global__ __launch_bounds__(256)
void sage_scatter_x(const int* __restrict__ esrc, const int* __restrict__ edst,
                    int* __restrict__ cursor, int* __restrict__ csr) {
  const int bucket = blockIdx.x & 7;
  const int e0 = (blockIdx.x >> 3) * 4096 + threadIdx.x;
#pragma unroll
  for (int j = 0; j < 16; ++j) {
    const int e = e0 + j * 256;
    if (e < NE) {
      const int d = edst[e];
      if (d / BDIV == bucket) {
        const int p = atomicAdd(&cursor[d], 1);
        csr[p] = esrc[e];
      }
    }
  }
}

// ------------- aggregation: mean over in-neighbors -------------
// wave per node; lane owns 2 of 128 fp16 channels, fp32 accumulate.
__global__ __launch_bounds__(256)
void sage_agg1(const int* __restrict__ offs, const int* __restrict__ csr,
               const u16* __restrict__ xh, u16* __restrict__ aggh) {
  const int node = blockIdx.x * 4 + (threadIdx.x >> 6);
  const int lane = threadIdx.x & 63;
  if (node >= NN) return;
  const int beg = offs[node], end = offs[node + 1];
  float ax = 0.f, ay = 0.f;
  const u16* xbase = xh + lane * 2;
  int e = beg;
  for (; e + 4 <= end; e += 4) {
    const int i0 = csr[e], i1 = csr[e + 1], i2 = csr[e + 2], i3 = csr[e + 3];
    const u32 v0 = *(const u32*)(xbase + i0 * C1);
    const u32 v1 = *(const u32*)(xbase + i1 * C1);
    const u32 v2 = *(const u32*)(xbase + i2 * C1);
    const u32 v3 = *(const u32*)(xbase + i3 * C1);
    ax += h2f(v0 & 0xffffu) + h2f(v1 & 0xffffu) + h2f(v2 & 0xffffu) + h2f(v3 & 0xffffu);
    ay += h2f(v0 >> 16) + h2f(v1 >> 16) + h2f(v2 >> 16) + h2f(v3 >> 16);
  }
  for (; e < end; ++e) {
    const u32 v = *(const u32*)(xbase + csr[e] * C1);
    ax += h2f(v & 0xffffu);
    ay += h2f(v >> 16);
  }
  const float inv = 1.0f / fmaxf((float)(end - beg), 1.0f);
  *(u32*)(aggh + node * C1 + lane * 2) = packh2(ax * inv, ay * inv);
}

// mean of t over in-neighbors; t = cols 0..63 of out128 [NN][128] fp16.
// wave per node, 2 edges in flight (half-wave each), shfl_xor(32) combine.
__global__ __launch_bounds__(256)
void sage_agg2(const int* __restrict__ offs, const int* __restrict__ csr,
               const u16* __restrict__ o128, float* __restrict__ agg) {
  const int node = blockIdx.x * 4 + (threadIdx.x >> 6);
  const int lane = threadIdx.x & 63;
  if (node >= NN) return;
  const int beg = offs[node], end = offs[node + 1];
  const int hf = lane >> 5, l = lane & 31;
  const u16* tb = o128 + l * 2;                       // channels 2l, 2l+1
  float ax = 0.f, ay = 0.f;
  int e = beg + hf;
  for (; e + 2 < end; e += 4) {
    const int s0 = csr[e], s1 = csr[e + 2];
    const u32 v0 = *(const u32*)(tb + s0 * 128);
    const u32 v1 = *(const u32*)(tb + s1 * 128);
    ax += h2f(v0 & 0xffffu) + h2f(v1 & 0xffffu);
    ay += h2f(v0 >> 16) + h2f(v1 >> 16);
  }
  if (e < end) {
    const u32 v = *(const u32*)(tb + csr[e] * 128);
    ax += h2f(v & 0xffffu);
    ay += h2f(v >> 16);
  }
  ax += __shfl_xor(ax, 32);
  ay += __shfl_xor(ay, 32);
  if (hf == 0) {
    const float inv = 1.0f / fmaxf((float)(end - beg), 1.0f);
    *(float2*)(agg + node * C2 + l * 2) = make_float2(ax * inv, ay * inv);
  }
}

// ------------- MFMA GEMM 1: H = relu(A1@W1l + A2@W1r + b1), fp16 out -------
// Block 256 (4 waves), 64 rows/block. LDS: two 64x128 fp16 tiles, 16B chunks
// XOR-swizzled (chunk ^= row&7) for conflict-free ds_read_b128.
// wt1 is [128 n][256 k] fp16. Wave w owns rows w*16..w*16+15, all 128 cols.
__global__ __launch_bounds__(256)
void sage_mgemm1(const u16* __restrict__ A1, const u16* __restrict__ A2,
                 const u16* __restrict__ wt1, const float* __restrict__ bias,
                 u16* __restrict__ H) {
  __shared__ __align__(16) u16 As[2][64][128];
  const int t = threadIdx.x;
  const int r0 = blockIdx.x * 64;
#pragma unroll
  for (int i = 0; i < 8; ++i) {                       // 2048 16B-chunk loads
    const int id = i * 256 + t;
    const int buf = id >> 10;
    const int id2 = id & 1023;
    const int row = id2 >> 4, c = id2 & 15;
    int gr = r0 + row; gr = (gr < NN) ? gr : NN - 1;  // clamp; store guarded
    const uint4 v = *(const uint4*)((buf ? A2 : A1) + (size_t)gr * 128 + c * 8);
    *(uint4*)(&As[buf][row][(c ^ (row & 7)) * 8]) = v;
  }
  __syncthreads();
  const int w = t >> 6, l = t & 63;
  const int lr = l & 15, lk = l >> 4;
  const int rowl = w * 16 + lr;                       // A-frag local row
  f32x4 acc[8];
#pragma unroll
  for (int c = 0; c < 8; ++c) acc[c] = (f32x4){0.f, 0.f, 0.f, 0.f};
#pragma unroll
  for (int kt = 0; kt < 8; ++kt) {                    // K = 256 in 32-steps
    const int buf = kt >> 2, kk = kt & 3;
    const int ch = (kk * 4 + lk) ^ (rowl & 7);
    const f16x8 a = *(const f16x8*)(&As[buf][rowl][ch * 8]);
#pragma unroll
    for (int c = 0; c < 8; ++c) {
      const f16x8 b = *(const f16x8*)(wt1 + ((c * 16 + lr) * 256 + kt * 32 + lk * 8));
      acc[c] = __builtin_amdgcn_mfma_f32_16x16x32_f16(a, b, acc[c], 0, 0, 0);
    }
  }
#pragma unroll
  for (int c = 0; c < 8; ++c) {                       // C/D: col=l&15, row=lk*4+j
    const int col = c * 16 + lr;
    const float bv = bias[col];
#pragma unroll
    for (int j = 0; j < 4; ++j) {
      const int row = r0 + w * 16 + lk * 4 + j;
      if (row < NN) H[(size_t)row * 128 + col] = f2h(fmaxf(acc[c][j] + bv, 0.f));
    }
  }
}

// ------------- MFMA GEMM 2: O = H @ [W2l | W2r], fp16 out [NN][128] -------
// cols 0..63 = t = h@W2l, cols 64..127 = t2 = h@W2r. No bias here (b2 is
// added once in pooling). wt2 is [128 n][128 k] fp16.
__global__ __launch_bounds__(256)
void sage_mgemm2(const u16* __restrict__ A, const u16* __restrict__ wt2,
                 u16* __restrict__ O) {
  __shared__ __align__(16) u16 As[64][128];
  const int t = threadIdx.x;
  const int r0 = blockIdx.x * 64;
#pragma unroll
  for (int i = 0; i < 4; ++i) {                       // 1024 16B-chunk loads
    const int id = i * 256 + t;
    const int row = id >> 4, c = id & 15;
    int gr = r0 + row; gr = (gr < NN) ? gr : NN - 1;
    const uint4 v = *(const uint4*)(A + (size_t)gr * 128 + c * 8);
    *(uint4*)(&As[row][(c ^ (row & 7)) * 8]) = v;
  }
  __syncthreads();
  const int w = t >> 6, l = t & 63;
  const int lr = l & 15, lk = l >> 4;
  const int rowl = w * 16 + lr;
  f32x4 acc[8];
#pragma unroll
  for (int c = 0; c < 8; ++c) acc[c] = (f32x4){0.f, 0.f, 0.f, 0.f};
#pragma unroll
  for (int kt = 0; kt < 4; ++kt) {                    // K = 128
    const int ch = (kt * 4 + lk) ^ (rowl & 7);
    const f16x8 a = *(const f16x8*)(&As[rowl][ch * 8]);
#pragma unroll
    for (int c = 0; c < 8; ++c) {
      const f16x8 b = *(const f16x8*)(wt2 + ((c * 16 + lr) * 128 + kt * 32 + lk * 8));
      acc[c] = __builtin_amdgcn_mfma_f32_16x16x32_f16(a, b, acc[c], 0, 0, 0);
    }
  }
#pragma unroll
  for (int c = 0; c < 8; ++c) {
    const int col = c * 16 + lr;
#pragma unroll
    for (int j = 0; j < 4; ++j) {
      const int row = r0 + w * 16 + lk * 4 + j;
      if (row < NN) O[(size_t)row * 128 + col] = f2h(acc[c][j]);
    }
  }
}

// ------------- pooling -------------
__global__ __launch_bounds__(256)
void sage_gcnt(const int* __restrict__ batch, int* __restrict__ gcnt) {
  const int n = blockIdx.x * 256 + threadIdx.x;
  if (n < NN) atomicAdd(&gcnt[batch[n]], 1);
}

// per node-channel: v = t2 (o128 col 64+c) + agg2 + b2[c]; atomic into pool.
__global__ __launch_bounds__(256)
void sage_pool(const u16* __restrict__ o128, const float* __restrict__ agg2,
               const float* __restrict__ b2, const int* __restrict__ batch,
               float* __restrict__ pool) {
  const int i = blockIdx.x * 256 + threadIdx.x;
  if (i >= NN * C2) return;
  const int n = i >> 6, c = i & 63;
  const float v = h2f(o128[(size_t)n * 128 + 64 + c]) + agg2[i] + b2[c];
  atomicAdd(&pool[batch[n] * C2 + c], v);
}

__global__ __launch_bounds__(256)
void sage_out(const float* __restrict__ pool, const int* __restrict__ gcnt,
              float* __restrict__ out) {
  const int i = blockIdx.x * 256 + threadIdx.x;
  if (i >= NG * C2) return;
  out[i] = pool[i] / fmaxf((float)gcnt[i >> 6], 1.0f);
}

extern "C" void kernel_launch(void* const* d_in, const int* in_sizes, int n_in,
                              void* d_out, int out_size, void* d_ws, size_t ws_size,
                              hipStream_t stream) {
  (void)in_sizes; (void)n_in; (void)out_size; (void)ws_size;
  const float* x     = (const float*)d_in[0];
  const float* W1l   = (const float*)d_in[1];
  const float* b1    = (const float*)d_in[2];
  const float* W1r   = (const float*)d_in[3];
  const float* W2l   = (const float*)d_in[4];
  const float* b2    = (const float*)d_in[5];
  const float* W2r   = (const float*)d_in[6];
  const int*   ei    = (const int*)d_in[7];   // [2, NE]: row0 = src, row1 = dst
  const int*   batch = (const int*)d_in[8];
  const int* esrc = ei;
  const int* edst = ei + NE;
  float* out = (float*)d_out;

  // ---- workspace carve-out (~91 MB) ----
  char* base = (char*)d_ws;
  size_t off = 0;
  auto take = [&](size_t bytes) -> char* {
    char* p = base + off;
    off += (bytes + 255) & ~(size_t)255;
    return p;
  };
  int* deg      = (int*)take((size_t)NN * 4);
  int* offs     = (int*)take((size_t)(NN + 1) * 4);
  int* cursor   = (int*)take((size_t)NN * 4);
  int* partials = (int*)take(1024 * 4);
  int* csr      = (int*)take((size_t)NE * 4);
  char* bufA    = take((size_t)NN * 256);   // xh (f16 NNx128) -> out128 (f16 NNx128)
  char* bufB    = take((size_t)NN * 256);   // agg1 (f16 NNx128) -> agg2 (f32 NNx64)
  u16*  hb      = (u16*)take((size_t)NN * 256);
  float* pool   = (float*)take((size_t)NG * C2 * 4);
  int*  gcnt    = (int*)take((size_t)NG * 4);
  u16*  wt1     = (u16*)take((size_t)128 * 256 * 2);
  u16*  wt2     = (u16*)take((size_t)128 * 128 * 2);

  u16*   xh    = (u16*)bufA;
  u16*   o128  = (u16*)bufA;                // gemm2 out (xh dead by then)
  u16*   agg1h = (u16*)bufB;
  float* agg2  = (float*)bufB;

  hipMemsetAsync(deg, 0, (size_t)NN * 4, stream);
  hipMemsetAsync(pool, 0, (size_t)NG * C2 * 4, stream);
  hipMemsetAsync(gcnt, 0, (size_t)NG * 4, stream);

  constexpr int SB = (NN + 511) / 512;      // scan blocks (196 <= 256)

  sage_wprep<<<192, 256, 0, stream>>>(W1l, W1r, W2l, W2r, wt1, wt2);
  sage_x2h<<<(NN * C1 / 4 + 255) / 256, 256, 0, stream>>>(x, xh);
  sage_deg<<<(NE + 255) / 256, 256, 0, stream>>>(edst, deg);
  sage_scan1<<<SB, 512, 0, stream>>>(deg, offs, partials);
  sage_scan2<<<1, 256, 0, stream>>>(partials, SB);
  sage_scan3<<<SB, 512, 0, stream>>>(offs, partials, cursor);
  sage_scatter_x<<<((NE + 4095) / 4096) * NBUCK, 256, 0, stream>>>(esrc, edst, cursor, csr);

  // layer 1
  sage_agg1<<<(NN + 3) / 4, 256, 0, stream>>>(offs, csr, xh, agg1h);
  sage_mgemm1<<<(NN + 63) / 64, 256, 0, stream>>>(agg1h, xh, wt1, b1, hb);

  // layer 2 (transform-then-aggregate: mean(h)@W2l == mean(h@W2l));
  // o128 = h @ [W2l | W2r]  (cols 0..63 = t, 64..127 = t2)
  sage_mgemm2<<<(NN + 63) / 64, 256, 0, stream>>>(hb, wt2, o128);
  sage_agg2<<<(NN + 3) / 4, 256, 0, stream>>>(offs, csr, o128, agg2);

  // global mean pool
  sage_gcnt<<<(NN + 255) / 256, 256, 0, stream>>>(batch, gcnt);
  sage_pool<<<(NN * C2 + 255) / 256, 256, 0, stream>>>(o128, agg2, b2, batch, pool);
  sage_out<<<(NG * C2 + 255) / 256, 256, 0, stream>>>(pool, gcnt, out);
}

// Round 6
// 491.936 us; speedup vs baseline: 1.9697x; 1.3959x over previous
//
#include <hip/hip_runtime.h>

// GraphSAGE (2x SAGEConv mean + global_mean_pool) on MI355X.
// R5: CSR build reworked as partition-then-build to kill dirty-line-lifetime
// write amplification (R4 profile: WRITE 173MB for 12.8MB csr because each
// line's 16 writes spanned the whole 12.8MB edge stream -> L2 evicted partial
// lines ~13x). New: (1) 196-bucket edge partition (bucket = dst>>9, packed
// (src<<9)|(dst&511) u32, block-reserved contiguous runs); (2) per-bucket
// one-block CSR build with LDS deg/scan/cursors - csr window 64KB, lifetime
// = one block. Replaces deg + 3 scans + scatter. Also: pool uses sorted-batch
// run accumulation (6.4M -> ~0.5M atomics). gpart aliases hb (dead by mgemm1).

constexpr int NN = 100000;    // nodes
constexpr int NE = 3200000;   // edges
constexpr int C1 = 128;       // IN_C == HID_C
constexpr int C2 = 64;        // OUT_C
constexpr int NG = 1024;      // graphs

constexpr int NBK = (NN + 511) >> 9;   // 196 buckets of 512 nodes

typedef unsigned int u32;
typedef unsigned short u16;
typedef _Float16 f16;
typedef f16 f16x8 __attribute__((ext_vector_type(8)));
typedef float f32x4 __attribute__((ext_vector_type(4)));

__device__ __forceinline__ float h2f(u32 bits16) {
  f16 h; u16 b = (u16)bits16;
  __builtin_memcpy(&h, &b, 2);
  return (float)h;
}
__device__ __forceinline__ u16 f2h(float f) {
  f16 h = (f16)f; u16 b;
  __builtin_memcpy(&b, &h, 2);
  return b;
}
__device__ __forceinline__ u32 packh2(float a, float b) {
  return (u32)f2h(a) | ((u32)f2h(b) << 16);
}

// ---------------- x -> fp16 ----------------
__global__ __launch_bounds__(256)
void sage_x2h(const float* __restrict__ x, u16* __restrict__ xh) {
  const int i = blockIdx.x * 256 + threadIdx.x;       // one float4 per thread
  if (i >= NN * C1 / 4) return;
  const float4 v = ((const float4*)x)[i];
  uint2 o;
  o.x = packh2(v.x, v.y);
  o.y = packh2(v.z, v.w);
  ((uint2*)xh)[i] = o;
}

// ------------- weights -> fp16, transposed [N][K] -------------
// wt1: [128 n][256 k]  (k<128: W1l, k>=128: W1r)    for gemm1
// wt2: [128 n][128 k]  (n<64: W2l col n, n>=64: W2r col n-64) for gemm2
__global__ __launch_bounds__(256)
void sage_wprep(const float* __restrict__ W1l, const float* __restrict__ W1r,
                const float* __restrict__ W2l, const float* __restrict__ W2r,
                u16* __restrict__ wt1, u16* __restrict__ wt2) {
  const int id = blockIdx.x * 256 + threadIdx.x;
  if (id < 128 * 256) {
    const int n = id >> 8, k = id & 255;
    const float v = (k < 128) ? W1l[k * 128 + n] : W1r[(k - 128) * 128 + n];
    wt1[id] = f2h(v);
  } else if (id < 128 * 256 + 128 * 128) {
    const int id2 = id - 128 * 256;
    const int n = id2 >> 7, k = id2 & 127;
    const float v = (n < 64) ? W2l[k * 64 + n] : W2r[k * 64 + (n - 64)];
    wt2[id2] = f2h(v);
  }
}

// ---------------- CSR build v2: partition by dst bucket ----------------
// k1: global bucket histogram (LDS-staged).
__global__ __launch_bounds__(256)
void sage_phist(const int* __restrict__ edst, int* __restrict__ ghist) {
  __shared__ int h[NBK];
  for (int i = threadIdx.x; i < NBK; i += 256) h[i] = 0;
  __syncthreads();
  const int e0 = blockIdx.x * 4096 + threadIdx.x;
#pragma unroll
  for (int j = 0; j < 16; ++j) {
    const int e = e0 + j * 256;
    if (e < NE) atomicAdd(&h[edst[e] >> 9], 1);
  }
  __syncthreads();
  for (int i = threadIdx.x; i < NBK; i += 256)
    if (h[i]) atomicAdd(&ghist[i], h[i]);
}

// k2: exclusive scan of 196 bucket counts -> bbase (and seed gcur).
__global__ __launch_bounds__(256)
void sage_pscan(const int* __restrict__ ghist, int* __restrict__ bbase,
                int* __restrict__ gcur) {
  __shared__ int s[256];
  const int t = threadIdx.x;
  const int v = (t < NBK) ? ghist[t] : 0;
  s[t] = v;
  __syncthreads();
  for (int d = 1; d < 256; d <<= 1) {
    const int a = (t >= d) ? s[t - d] : 0;
    __syncthreads();
    s[t] += a;
    __syncthreads();
  }
  if (t < NBK) { bbase[t] = s[t] - v; gcur[t] = s[t] - v; }
  if (t == 0) bbase[NBK] = NE;
}

// k3: partition edges into bucket-contiguous runs of packed (src<<9)|(dst&511).
// Per block: LDS chunk histogram -> one global atomicAdd per bucket to reserve
// a contiguous run -> scatter. Runs ~21 entries -> near-full-line writes.
__global__ __launch_bounds__(256)
void sage_part(const int* __restrict__ esrc, const int* __restrict__ edst,
               int* __restrict__ gcur, u32* __restrict__ gpart) {
  __shared__ int h[NBK], cur[NBK];
  for (int i = threadIdx.x; i < NBK; i += 256) h[i] = 0;
  __syncthreads();
  const int e0 = blockIdx.x * 4096 + threadIdx.x;
#pragma unroll
  for (int j = 0; j < 16; ++j) {
    const int e = e0 + j * 256;
    if (e < NE) atomicAdd(&h[edst[e] >> 9], 1);
  }
  __syncthreads();
  for (int i = threadIdx.x; i < NBK; i += 256)
    cur[i] = h[i] ? atomicAdd(&gcur[i], h[i]) : 0;
  __syncthreads();
#pragma unroll
  for (int j = 0; j < 16; ++j) {
    const int e = e0 + j * 256;
    if (e < NE) {
      const int d = edst[e];
      const int p = atomicAdd(&cur[d >> 9], 1);
      gpart[p] = ((u32)esrc[e] << 9) | (u32)(d & 511);
    }
  }
}

// k4: one block per bucket: LDS degree hist -> scan -> offs (coalesced) ->
// csr scatter into the bucket's ~64KB window (single block, short lifetime).
__global__ __launch_bounds__(512)
void sage_bbuild(const int* __restrict__ bbase, const u32* __restrict__ gpart,
                 int* __restrict__ offs, int* __restrict__ csr) {
  __shared__ int ldeg[512], lcur[512], ssc[512];
  const int b = blockIdx.x, t = threadIdx.x;
  const int e0 = bbase[b], cnt = bbase[b + 1] - e0;
  ldeg[t] = 0;
  __syncthreads();
  for (int e = t; e < cnt; e += 512)
    atomicAdd(&ldeg[gpart[e0 + e] & 511], 1);
  __syncthreads();
  const int v = ldeg[t];
  ssc[t] = v;
  __syncthreads();
  for (int d = 1; d < 512; d <<= 1) {
    const int a = (t >= d) ? ssc[t - d] : 0;
    __syncthreads();
    ssc[t] += a;
    __syncthreads();
  }
  const int pre = ssc[t] - v;
  lcur[t] = pre;
  const int node = b * 512 + t;
  if (node < NN) offs[node] = e0 + pre;
  if (b == 0 && t == 0) offs[NN] = NE;
  __syncthreads();
  for (int e = t; e < cnt; e += 512) {
    const u32 pk = gpart[e0 + e];
    const int p = atomicAdd(&lcur[pk & 511], 1);
    csr[e0 + p] = (int)(pk >> 9);
  }
}

// ------------- aggregation: mean over in-neighbors -------------
// wave per node; lane owns 2 of 128 fp16 channels, fp32 accumulate.
__global__ __launch_bounds__(256)
void sage_agg1(const int* __restrict__ offs, const int* __restrict__ csr,
               const u16* __restrict__ xh, u16* __restrict__ aggh) {
  const int node = blockIdx.x * 4 + (threadIdx.x >> 6);
  const int lane = threadIdx.x & 63;
  if (node >= NN) return;
  const int beg = offs[node], end = offs[node + 1];
  float ax = 0.f, ay = 0.f;
  const u16* xbase = xh + lane * 2;
  int e = beg;
  for (; e + 4 <= end; e += 4) {
    const int i0 = csr[e], i1 = csr[e + 1], i2 = csr[e + 2], i3 = csr[e + 3];
    const u32 v0 = *(const u32*)(xbase + i0 * C1);
    const u32 v1 = *(const u32*)(xbase + i1 * C1);
    const u32 v2 = *(const u32*)(xbase + i2 * C1);
    const u32 v3 = *(const u32*)(xbase + i3 * C1);
    ax += h2f(v0 & 0xffffu) + h2f(v1 & 0xffffu) + h2f(v2 & 0xffffu) + h2f(v3 & 0xffffu);
    ay += h2f(v0 >> 16) + h2f(v1 >> 16) + h2f(v2 >> 16) + h2f(v3 >> 16);
  }
  for (; e < end; ++e) {
    const u32 v = *(const u32*)(xbase + csr[e] * C1);
    ax += h2f(v & 0xffffu);
    ay += h2f(v >> 16);
  }
  const float inv = 1.0f / fmaxf((float)(end - beg), 1.0f);
  *(u32*)(aggh + node * C1 + lane * 2) = packh2(ax * inv, ay * inv);
}

// mean of t over in-neighbors; t = cols 0..63 of o128 [NN][128] fp16.
// wave per node, 2 edges in flight (half-wave each), shfl_xor(32) combine.
__global__ __launch_bounds__(256)
void sage_agg2(const int* __restrict__ offs, const int* __restrict__ csr,
               const u16* __restrict__ o128, float* __restrict__ agg) {
  const int node = blockIdx.x * 4 + (threadIdx.x >> 6);
  const int lane = threadIdx.x & 63;
  if (node >= NN) return;
  const int beg = offs[node], end = offs[node + 1];
  const int hf = lane >> 5, l = lane & 31;
  const u16* tb = o128 + l * 2;                       // channels 2l, 2l+1
  float ax = 0.f, ay = 0.f;
  int e = beg + hf;
  for (; e + 2 < end; e += 4) {
    const int s0 = csr[e], s1 = csr[e + 2];
    const u32 v0 = *(const u32*)(tb + s0 * 128);
    const u32 v1 = *(const u32*)(tb + s1 * 128);
    ax += h2f(v0 & 0xffffu) + h2f(v1 & 0xffffu);
    ay += h2f(v0 >> 16) + h2f(v1 >> 16);
  }
  if (e < end) {
    const u32 v = *(const u32*)(tb + csr[e] * 128);
    ax += h2f(v & 0xffffu);
    ay += h2f(v >> 16);
  }
  ax += __shfl_xor(ax, 32);
  ay += __shfl_xor(ay, 32);
  if (hf == 0) {
    const float inv = 1.0f / fmaxf((float)(end - beg), 1.0f);
    *(float2*)(agg + node * C2 + l * 2) = make_float2(ax * inv, ay * inv);
  }
}

// ------------- MFMA GEMM 1: H = relu(A1@W1l + A2@W1r + b1), fp16 out -------
// Block 256 (4 waves), 64 rows/block. LDS: two 64x128 fp16 tiles, 16B chunks
// XOR-swizzled (chunk ^= row&7) for conflict-free ds_read_b128.
// wt1 is [128 n][256 k] fp16. Wave w owns rows w*16..w*16+15, all 128 cols.
__global__ __launch_bounds__(256)
void sage_mgemm1(const u16* __restrict__ A1, const u16* __restrict__ A2,
                 const u16* __restrict__ wt1, const float* __restrict__ bias,
                 u16* __restrict__ H) {
  __shared__ __align__(16) u16 As[2][64][128];
  const int t = threadIdx.x;
  const int r0 = blockIdx.x * 64;
#pragma unroll
  for (int i = 0; i < 8; ++i) {                       // 2048 16B-chunk loads
    const int id = i * 256 + t;
    const int buf = id >> 10;
    const int id2 = id & 1023;
    const int row = id2 >> 4, c = id2 & 15;
    int gr = r0 + row; gr = (gr < NN) ? gr : NN - 1;  // clamp; store guarded
    const uint4 v = *(const uint4*)((buf ? A2 : A1) + (size_t)gr * 128 + c * 8);
    *(uint4*)(&As[buf][row][(c ^ (row & 7)) * 8]) = v;
  }
  __syncthreads();
  const int w = t >> 6, l = t & 63;
  const int lr = l & 15, lk = l >> 4;
  const int rowl = w * 16 + lr;                       // A-frag local row
  f32x4 acc[8];
#pragma unroll
  for (int c = 0; c < 8; ++c) acc[c] = (f32x4){0.f, 0.f, 0.f, 0.f};
#pragma unroll
  for (int kt = 0; kt < 8; ++kt) {                    // K = 256 in 32-steps
    const int buf = kt >> 2, kk = kt & 3;
    const int ch = (kk * 4 + lk) ^ (rowl & 7);
    const f16x8 a = *(const f16x8*)(&As[buf][rowl][ch * 8]);
#pragma unroll
    for (int c = 0; c < 8; ++c) {
      const f16x8 b = *(const f16x8*)(wt1 + ((c * 16 + lr) * 256 + kt * 32 + lk * 8));
      acc[c] = __builtin_amdgcn_mfma_f32_16x16x32_f16(a, b, acc[c], 0, 0, 0);
    }
  }
#pragma unroll
  for (int c = 0; c < 8; ++c) {                       // C/D: col=l&15, row=lk*4+j
    const int col = c * 16 + lr;
    const float bv = bias[col];
#pragma unroll
    for (int j = 0; j < 4; ++j) {
      const int row = r0 + w * 16 + lk * 4 + j;
      if (row < NN) H[(size_t)row * 128 + col] = f2h(fmaxf(acc[c][j] + bv, 0.f));
    }
  }
}

// ------------- MFMA GEMM 2: O = H @ [W2l | W2r], fp16 out [NN][128] -------
// cols 0..63 = t = h@W2l, cols 64..127 = t2 = h@W2r. No bias here (b2 is
// added once in pooling). wt2 is [128 n][128 k] fp16.
__global__ __launch_bounds__(256)
void sage_mgemm2(const u16* __restrict__ A, const u16* __restrict__ wt2,
                 u16* __restrict__ O) {
  __shared__ __align__(16) u16 As[64][128];
  const int t = threadIdx.x;
  const int r0 = blockIdx.x * 64;
#pragma unroll
  for (int i = 0; i < 4; ++i) {                       // 1024 16B-chunk loads
    const int id = i * 256 + t;
    const int row = id >> 4, c = id & 15;
    int gr = r0 + row; gr = (gr < NN) ? gr : NN - 1;
    const uint4 v = *(const uint4*)(A + (size_t)gr * 128 + c * 8);
    *(uint4*)(&As[row][(c ^ (row & 7)) * 8]) = v;
  }
  __syncthreads();
  const int w = t >> 6, l = t & 63;
  const int lr = l & 15, lk = l >> 4;
  const int rowl = w * 16 + lr;
  f32x4 acc[8];
#pragma unroll
  for (int c = 0; c < 8; ++c) acc[c] = (f32x4){0.f, 0.f, 0.f, 0.f};
#pragma unroll
  for (int kt = 0; kt < 4; ++kt) {                    // K = 128
    const int ch = (kt * 4 + lk) ^ (rowl & 7);
    const f16x8 a = *(const f16x8*)(&As[rowl][ch * 8]);
#pragma unroll
    for (int c = 0; c < 8; ++c) {
      const f16x8 b = *(const f16x8*)(wt2 + ((c * 16 + lr) * 128 + kt * 32 + lk * 8));
      acc[c] = __builtin_amdgcn_mfma_f32_16x16x32_f16(a, b, acc[c], 0, 0, 0);
    }
  }
#pragma unroll
  for (int c = 0; c < 8; ++c) {
    const int col = c * 16 + lr;
#pragma unroll
    for (int j = 0; j < 4; ++j) {
      const int row = r0 + w * 16 + lk * 4 + j;
      if (row < NN) O[(size_t)row * 128 + col] = f2h(acc[c][j]);
    }
  }
}

// ------------- pooling -------------
__global__ __launch_bounds__(256)
void sage_gcnt(const int* __restrict__ batch, int* __restrict__ gcnt) {
  const int n = blockIdx.x * 256 + threadIdx.x;
  if (n < NN) atomicAdd(&gcnt[batch[n]], 1);
}

// batch is sorted: accumulate runs locally, flush one atomic per graph change.
// Block covers 128 nodes; thread t owns channel c=t&63, walks nodes (t>>6)+4k.
__global__ __launch_bounds__(256)
void sage_pool2(const u16* __restrict__ o128, const float* __restrict__ agg2,
                const float* __restrict__ b2, const int* __restrict__ batch,
                float* __restrict__ pool) {
  const int t = threadIdx.x;
  const int c = t & 63, sl = t >> 6;
  const int n0 = blockIdx.x * 128;
  const float bv = b2[c];
  float acc = 0.f;
  int curg = -1;
  for (int n = n0 + sl; n < n0 + 128 && n < NN; n += 4) {
    const int g = batch[n];
    const float v = h2f(o128[(size_t)n * 128 + 64 + c]) + agg2[n * C2 + c] + bv;
    if (g != curg) {
      if (curg >= 0) atomicAdd(&pool[curg * C2 + c], acc);
      curg = g;
      acc = v;
    } else {
      acc += v;
    }
  }
  if (curg >= 0) atomicAdd(&pool[curg * C2 + c], acc);
}

__global__ __launch_bounds__(256)
void sage_out(const float* __restrict__ pool, const int* __restrict__ gcnt,
              float* __restrict__ out) {
  const int i = blockIdx.x * 256 + threadIdx.x;
  if (i >= NG * C2) return;
  out[i] = pool[i] / fmaxf((float)gcnt[i >> 6], 1.0f);
}

extern "C" void kernel_launch(void* const* d_in, const int* in_sizes, int n_in,
                              void* d_out, int out_size, void* d_ws, size_t ws_size,
                              hipStream_t stream) {
  (void)in_sizes; (void)n_in; (void)out_size; (void)ws_size;
  const float* x     = (const float*)d_in[0];
  const float* W1l   = (const float*)d_in[1];
  const float* b1    = (const float*)d_in[2];
  const float* W1r   = (const float*)d_in[3];
  const float* W2l   = (const float*)d_in[4];
  const float* b2    = (const float*)d_in[5];
  const float* W2r   = (const float*)d_in[6];
  const int*   ei    = (const int*)d_in[7];   // [2, NE]: row0 = src, row1 = dst
  const int*   batch = (const int*)d_in[8];
  const int* esrc = ei;
  const int* edst = ei + NE;
  float* out = (float*)d_out;

  // ---- workspace carve-out (~91 MB) ----
  char* base = (char*)d_ws;
  size_t off = 0;
  auto take = [&](size_t bytes) -> char* {
    char* p = base + off;
    off += (bytes + 255) & ~(size_t)255;
    return p;
  };
  int* ghist    = (int*)take((size_t)NBK * 4);
  int* bbase    = (int*)take((size_t)(NBK + 1) * 4);
  int* gcur     = (int*)take((size_t)NBK * 4);
  int* offs     = (int*)take((size_t)(NN + 1) * 4);
  int* csr      = (int*)take((size_t)NE * 4);
  char* bufA    = take((size_t)NN * 256);   // xh (f16 NNx128) -> o128 (f16 NNx128)
  char* bufB    = take((size_t)NN * 256);   // agg1 (f16 NNx128) -> agg2 (f32 NNx64)
  char* bufC    = take((size_t)NN * 256);   // gpart (u32 NE=12.8MB) -> hb (f16 NNx128)
  float* pool   = (float*)take((size_t)NG * C2 * 4);
  int*  gcnt    = (int*)take((size_t)NG * 4);
  u16*  wt1     = (u16*)take((size_t)128 * 256 * 2);
  u16*  wt2     = (u16*)take((size_t)128 * 128 * 2);

  u16*   xh    = (u16*)bufA;
  u16*   o128  = (u16*)bufA;                // gemm2 out (xh dead by then)
  u16*   agg1h = (u16*)bufB;
  float* agg2  = (float*)bufB;
  u32*   gpart = (u32*)bufC;                // dead after bbuild
  u16*   hb    = (u16*)bufC;                // written by mgemm1 after that

  hipMemsetAsync(ghist, 0, (size_t)NBK * 4, stream);
  hipMemsetAsync(pool, 0, (size_t)NG * C2 * 4, stream);
  hipMemsetAsync(gcnt, 0, (size_t)NG * 4, stream);

  sage_wprep<<<192, 256, 0, stream>>>(W1l, W1r, W2l, W2r, wt1, wt2);
  sage_x2h<<<(NN * C1 / 4 + 255) / 256, 256, 0, stream>>>(x, xh);

  // CSR build v2
  const int PB = (NE + 4095) / 4096;        // 782 partition blocks
  sage_phist<<<PB, 256, 0, stream>>>(edst, ghist);
  sage_pscan<<<1, 256, 0, stream>>>(ghist, bbase, gcur);
  sage_part<<<PB, 256, 0, stream>>>(esrc, edst, gcur, gpart);
  sage_bbuild<<<NBK, 512, 0, stream>>>(bbase, gpart, offs, csr);

  // layer 1
  sage_agg1<<<(NN + 3) / 4, 256, 0, stream>>>(offs, csr, xh, agg1h);
  sage_mgemm1<<<(NN + 63) / 64, 256, 0, stream>>>(agg1h, xh, wt1, b1, hb);

  // layer 2 (transform-then-aggregate: mean(h)@W2l == mean(h@W2l));
  // o128 = h @ [W2l | W2r]  (cols 0..63 = t, 64..127 = t2)
  sage_mgemm2<<<(NN + 63) / 64, 256, 0, stream>>>(hb, wt2, o128);
  sage_agg2<<<(NN + 3) / 4, 256, 0, stream>>>(offs, csr, o128, agg2);

  // global mean pool
  sage_gcnt<<<(NN + 255) / 256, 256, 0, stream>>>(batch, gcnt);
  sage_pool2<<<(NN + 127) / 128, 256, 0, stream>>>(o128, agg2, b2, batch, pool);
  sage_out<<<(NG * C2 + 255) / 256, 256, 0, stream>>>(pool, gcnt, out);
}